// Round 8
// baseline (484.988 us; speedup 1.0000x reference)
//
#include <hip/hip_runtime.h>
#include <hip/hip_bf16.h>
#include <cstdint>

typedef __bf16 bf16;
typedef __bf16 bf16x8 __attribute__((ext_vector_type(8)));
typedef float f32x4 __attribute__((ext_vector_type(4)));
typedef __attribute__((address_space(3))) uint32_t lds_u32;
typedef const __attribute__((address_space(1))) uint32_t glb_u32;

#define B_ 2
#define H_ 32
#define HKV_ 8
#define S_ 2048
#define D_ 128
#define QT 128                 // 128 q-rows/block, 8 waves
#define KT 64
#define NQT (S_ / QT)          // 16 q-tiles
#define NTILES (S_ / KT)       // 32 k-tiles
#define TILE_ELEMS (KT * D_)   // 8192 bf16 = 16 KiB per tile image
#define PST 72                 // P LDS row stride: 144B/row, 16B-aligned
#define NEG_BIG (-1.0e30f)
#define SCL 0.12751745f        // (1/sqrt(128)) * log2(e): softmax in exp2 domain
#define DEFER_THR 8.0f         // T13: skip O-rescale while max grows < 2^8

__device__ __forceinline__ bf16x8 cvt8p(float4 a, float4 b) {
  bf16x8 r = {(bf16)a.x, (bf16)a.y, (bf16)a.z, (bf16)a.w,
              (bf16)b.x, (bf16)b.y, (bf16)b.z, (bf16)b.w};
  return r;
}
__device__ __forceinline__ bf16x8 cvt8(const float* f) {
  return cvt8p(*(const float4*)f, *(const float4*)(f + 4));
}

// ---------------- pre-pass: build swizzled bf16 LDS tile images in ws -------
// K image, per (bhkv,tile): byte(row*256 + c16*16) holds K[row][(c16^(row&7))*8 ..+7]
// V image (transposed):     byte(d*128  + c8*16)  holds V[(c8^(d&7))*8 + t][d], t=0..7
// LINEAR global->LDS copy then yields the XOR-swizzled layout (rule #21).
__global__ __launch_bounds__(512) void prep(const float* __restrict__ k,
                                            const float* __restrict__ v,
                                            bf16* __restrict__ kws,
                                            bf16* __restrict__ vws) {
  __shared__ float Vf[KT * 129];  // stride 129: conflict-free column reads
  const int blk = blockIdx.x;     // 512 = 16 (b*hkv) * 32 tiles
  const int bhkv = blk >> 5, tile = blk & 31;
  const float* ks = k + ((size_t)bhkv * S_ + (size_t)tile * KT) * D_;
  const float* vs = v + ((size_t)bhkv * S_ + (size_t)tile * KT) * D_;
  bf16* kd = kws + (size_t)blk * TILE_ELEMS;
  bf16* vd = vws + (size_t)blk * TILE_ELEMS;
  const int t = threadIdx.x;
#pragma unroll
  for (int i = 0; i < 4; ++i) {  // coalesced V tile -> LDS
    int c = t + 512 * i, row = c >> 5, c4 = c & 31;
    *(float4*)&Vf[row * 129 + c4 * 4] = *(const float4*)(vs + row * D_ + c4 * 4);
  }
#pragma unroll
  for (int i = 0; i < 2; ++i) {  // K image (coalesced read, linear write)
    int chunk = t + 512 * i, row = chunk >> 4, c16 = chunk & 15;
    int e = (c16 ^ (row & 7)) << 3;
    *(bf16x8*)&kd[chunk * 8] = cvt8(ks + row * D_ + e);
  }
  __syncthreads();
#pragma unroll
  for (int i = 0; i < 2; ++i) {  // V image from LDS transpose
    int chunk = t + 512 * i, d = chunk >> 3, c8 = chunk & 7;
    int k0 = (c8 ^ (d & 7)) << 3;
    bf16x8 val;
#pragma unroll
    for (int kk = 0; kk < 8; ++kk) val[kk] = (bf16)Vf[(k0 + kk) * 129 + d];
    *(bf16x8*)&vd[chunk * 8] = val;
  }
}

// ---------------- main: flash attention, QT=128 / 8 waves / 512 threads -----
// R8: (a) LPT block order -- tqt = 15-(bid>>6): the 64 longest blocks (32
// iters) launch first, short ones backfill; fixes the 23%-occupancy makespan
// problem of per-group descending order. (b) LDS diet 67.5K -> 50K: K single-
// buffered (restaged into the same buffer after a post-QK barrier; DMA hides
// under softmax+PV, mostly L2-hits per FETCH_SIZE) -> 3 blocks/CU, 6 waves/
// SIMD of independent work to fill the stall time the counters show.
__global__ __launch_bounds__(512, 6) void fa_mfma(
    const float* __restrict__ q, const bf16* __restrict__ kws,
    const bf16* __restrict__ vws, float* __restrict__ out) {
  __shared__ bf16 Kb[TILE_ELEMS];    // 16 KiB, single-buffered
  __shared__ bf16 Vb[TILE_ELEMS];    // 16 KiB
  __shared__ bf16 Ps[8 * 16 * PST];  // 18 KiB

  const int tid = threadIdx.x, wave = tid >> 6, lane = tid & 63;
  const int col = lane & 15, quad = lane >> 4;
  const int bid = blockIdx.x;
  const int tqt = (NQT - 1) - (bid >> 6);  // LPT: longest first
  const int bh = bid & 63, b = bh >> 5, h = bh & 31, hkv = h >> 2;  // GQA h/4
  const int bhkv = b * HKV_ + hkv;

  const float* qh = q + (size_t)(b * H_ + h) * S_ * D_;
  float* oh = out + (size_t)(b * H_ + h) * S_ * D_;
  const bf16* kg = kws + (size_t)(bhkv * NTILES) * TILE_ELEMS;
  const bf16* vg = vws + (size_t)(bhkv * NTILES) * TILE_ELEMS;
  const int q0 = tqt * QT;
  const int jmax = 2 * tqt + 1;  // k-tiles 0..jmax cover keys < q0+QT

  // Q A-fragments: A[m=col][k=quad*8+j], chunk ks covers d in [ks*32,ks*32+32)
  bf16x8 qf[4];
  {
    const float* qrow = qh + (size_t)(q0 + wave * 16 + col) * D_ + quad * 8;
#pragma unroll
    for (int ks = 0; ks < 4; ++ks) qf[ks] = cvt8(qrow + ks * 32);
  }

  f32x4 o[8];
#pragma unroll
  for (int i = 0; i < 8; ++i) o[i] = (f32x4){0.f, 0.f, 0.f, 0.f};
  float m_i[4], lp[4];  // lp: per-lane PARTIAL l; reduced in the epilogue
#pragma unroll
  for (int r = 0; r < 4; ++r) { m_i[r] = NEG_BIG; lp[r] = 0.f; }

  // swizzled-read offsets (same involution as prep): qx[ks] for b128 reads
  const int qoff = (quad * 16) ^ ((col & 7) << 4);
  const int qx[4] = {qoff, qoff ^ 64, qoff ^ 128, qoff ^ 192};

  const int stoff = tid * 16;  // 512 threads x 16B = 8 KiB per pass

  auto stageK = [&](int j) {
    const char* src = (const char*)(kg + (size_t)j * TILE_ELEMS) + stoff;
    char* dst = (char*)Kb + stoff;
#pragma unroll
    for (int i = 0; i < 2; ++i)
      __builtin_amdgcn_global_load_lds((glb_u32*)(src + i * 8192),
                                       (lds_u32*)(dst + i * 8192), 16, 0, 0);
  };
  auto stageV = [&](int j) {
    const char* src = (const char*)(vg + (size_t)j * TILE_ELEMS) + stoff;
    char* dst = (char*)Vb + stoff;
#pragma unroll
    for (int i = 0; i < 2; ++i)
      __builtin_amdgcn_global_load_lds((glb_u32*)(src + i * 8192),
                                       (lds_u32*)(dst + i * 8192), 16, 0, 0);
  };

  stageK(0);
  asm volatile("s_waitcnt vmcnt(0)" ::: "memory");
  __builtin_amdgcn_s_barrier();
  __builtin_amdgcn_sched_barrier(0);

  for (int j = 0; j <= jmax; ++j) {
    stageV(j);  // DMA in flight under QK+softmax; needed at bar2

    // ---- S strip: 16 q-rows x 64 keys per wave (swizzled b128 reads) ----
    float s[4][4];  // S[qrow=wave*16+quad*4+r][key=nt*16+col]
    __builtin_amdgcn_s_setprio(1);
#pragma unroll
    for (int nt = 0; nt < 4; ++nt) {
      const char* An = (const char*)Kb + (nt * 16 + col) * 256;
      f32x4 acc = (f32x4){0.f, 0.f, 0.f, 0.f};
#pragma unroll
      for (int ks = 0; ks < 4; ++ks) {
        bf16x8 kf = *(const bf16x8*)(An + qx[ks]);
        acc = __builtin_amdgcn_mfma_f32_16x16x32_bf16(qf[ks], kf, acc, 0, 0, 0);
      }
#pragma unroll
      for (int r = 0; r < 4; ++r) s[nt][r] = acc[r] * SCL;
    }
    __builtin_amdgcn_s_setprio(0);

    // bar1: all waves' K-data is in registers -> Kb may be restaged
    asm volatile("" ::: "memory");
    __builtin_amdgcn_s_barrier();
    __builtin_amdgcn_sched_barrier(0);
    if (j < jmax) stageK(j + 1);  // DMA under softmax+PV; needed at bar3

    // causal mask: only the last two k-tiles intersect the diagonal
    if (j >= 2 * tqt) {
      const int rel = j * KT - q0 - wave * 16;  // key offset vs wave's row base
#pragma unroll
      for (int nt = 0; nt < 4; ++nt) {
        int kc = rel + nt * 16 + col;
#pragma unroll
        for (int r = 0; r < 4; ++r)
          if (kc > quad * 4 + r) s[nt][r] = NEG_BIG;
      }
    }

    // ---- online softmax: max-reduce only; l kept as per-lane partial ----
    float mx[4];
#pragma unroll
    for (int r = 0; r < 4; ++r) {
      float m0 = fmaxf(fmaxf(s[0][r], s[1][r]), fmaxf(s[2][r], s[3][r]));
#pragma unroll
      for (int off = 1; off < 16; off <<= 1)
        m0 = fmaxf(m0, __shfl_xor(m0, off, 64));
      mx[r] = m0;  // uniform across the row's 16 lanes
    }
    // T13 defer-max: wave-uniform skip of the O-rescale while growth < THR
    float need = fmaxf(fmaxf(mx[0] - m_i[0], mx[1] - m_i[1]),
                       fmaxf(mx[2] - m_i[2], mx[3] - m_i[3]));
    if (__any(need > DEFER_THR)) {
#pragma unroll
      for (int r = 0; r < 4; ++r) {
        float mnew = fmaxf(m_i[r], mx[r]);
        float alpha = exp2f(m_i[r] - mnew);
        lp[r] *= alpha;
        m_i[r] = mnew;
#pragma unroll
        for (int dt = 0; dt < 8; ++dt) o[dt][r] *= alpha;
      }
    }

    float p[4][4];
#pragma unroll
    for (int r = 0; r < 4; ++r) {
      float rs = 0.f;
#pragma unroll
      for (int nt = 0; nt < 4; ++nt) {
        float pv = exp2f(s[nt][r] - m_i[r]);  // bounded by 2^THR
        p[nt][r] = pv;
        rs += pv;
      }
      lp[r] += rs;
    }

    // ---- P: C-layout -> A-layout via per-wave LDS round trip ----
    bf16* pw = &Ps[wave * 16 * PST];
#pragma unroll
    for (int nt = 0; nt < 4; ++nt)
#pragma unroll
      for (int r = 0; r < 4; ++r)
        pw[(quad * 4 + r) * PST + nt * 16 + col] = (bf16)p[nt][r];

    // bar2 (counted): V(j) + P visible; K(j+1)'s 2 loads stay in flight
    if (j < jmax)
      asm volatile("s_waitcnt vmcnt(2) lgkmcnt(0)" ::: "memory");
    else
      asm volatile("s_waitcnt vmcnt(0) lgkmcnt(0)" ::: "memory");
    __builtin_amdgcn_s_barrier();
    __builtin_amdgcn_sched_barrier(0);

    bf16x8 pf[2];
#pragma unroll
    for (int ks = 0; ks < 2; ++ks)
      pf[ks] = *(const bf16x8*)&pw[col * PST + ks * 32 + quad * 8];

    // ---- O += P·V (swizzled single b128 reads) ----
    __builtin_amdgcn_s_setprio(1);
#pragma unroll
    for (int dt = 0; dt < 8; ++dt) {
      const char* Av = (const char*)Vb + (dt * 16 + col) * 128;
#pragma unroll
      for (int ks = 0; ks < 2; ++ks) {
        bf16x8 vf = *(const bf16x8*)(Av + qx[ks]);
        o[dt] = __builtin_amdgcn_mfma_f32_16x16x32_bf16(pf[ks], vf, o[dt], 0, 0, 0);
      }
    }
    __builtin_amdgcn_s_setprio(0);

    // bar3: K(j+1) complete + all Vb/Ps reads done -> safe to restage
    if (j < jmax) {
      asm volatile("s_waitcnt vmcnt(0)" ::: "memory");
      __builtin_amdgcn_s_barrier();
      __builtin_amdgcn_sched_barrier(0);
    }
  }

  // ---- epilogue: reduce partial l across the row's 16 lanes, O / l ----
#pragma unroll
  for (int r = 0; r < 4; ++r) {
    float l = lp[r];
#pragma unroll
    for (int off = 1; off < 16; off <<= 1)
      l += __shfl_xor(l, off, 64);
    float inv = 1.f / l;
    float* orow = oh + (size_t)(q0 + wave * 16 + quad * 4 + r) * D_;
#pragma unroll
    for (int dt = 0; dt < 8; ++dt)
      orow[dt * 16 + col] = o[dt][r] * inv;
  }
}

extern "C" void kernel_launch(void* const* d_in, const int* in_sizes, int n_in,
                              void* d_out, int out_size, void* d_ws, size_t ws_size,
                              hipStream_t stream) {
  const int QN = B_ * H_ * S_ * D_;
  int qi, ki, vi;
  if (in_sizes[0] == QN)      { qi = 0; ki = 1; vi = 2; }
  else if (in_sizes[1] == QN) { qi = 1; ki = 0; vi = 2; }
  else                        { qi = 2; ki = 0; vi = 1; }
  const float* q = (const float*)d_in[qi];
  const float* k = (const float*)d_in[ki];
  const float* v = (const float*)d_in[vi];
  float* out = (float*)d_out;

  // ws: K images then V images; 2 * 16*32*8192 bf16 = 16 MiB total
  bf16* kws = (bf16*)d_ws;
  bf16* vws = kws + (size_t)(B_ * HKV_) * NTILES * TILE_ELEMS;

  prep<<<dim3(B_ * HKV_ * NTILES), dim3(512), 0, stream>>>(k, v, kws, vws);
  fa_mfma<<<dim3(B_ * H_ * NQT), dim3(512), 0, stream>>>(q, kws, vws, out);
}

// Round 9
// 255.932 us; speedup vs baseline: 1.8950x; 1.8950x over previous
//
#include <hip/hip_runtime.h>
#include <hip/hip_bf16.h>
#include <cstdint>

typedef __bf16 bf16;
typedef __bf16 bf16x8 __attribute__((ext_vector_type(8)));
typedef float f32x4 __attribute__((ext_vector_type(4)));
typedef __attribute__((address_space(3))) uint32_t lds_u32;
typedef const __attribute__((address_space(1))) uint32_t glb_u32;

#define B_ 2
#define H_ 32
#define HKV_ 8
#define S_ 2048
#define D_ 128
#define QT 128                 // 128 q-rows/block, 8 waves
#define KT 64
#define NQT (S_ / QT)          // 16 q-tiles
#define NTILES (S_ / KT)       // 32 k-tiles
#define TILE_ELEMS (KT * D_)   // 8192 bf16 = 16 KiB per tile image
#define PST 72                 // P LDS row stride: 144B/row, 16B-aligned
#define NEG_BIG (-1.0e30f)
#define SCL 0.12751745f        // (1/sqrt(128)) * log2(e): softmax in exp2 domain
#define DEFER_THR 8.0f         // T13: skip O-rescale while max grows < 2^8

__device__ __forceinline__ bf16x8 cvt8p(float4 a, float4 b) {
  bf16x8 r = {(bf16)a.x, (bf16)a.y, (bf16)a.z, (bf16)a.w,
              (bf16)b.x, (bf16)b.y, (bf16)b.z, (bf16)b.w};
  return r;
}
__device__ __forceinline__ bf16x8 cvt8(const float* f) {
  return cvt8p(*(const float4*)f, *(const float4*)(f + 4));
}

// ---------------- pre-pass: build swizzled bf16 LDS tile images in ws -------
// K image, per (bhkv,tile): byte(row*256 + c16*16) holds K[row][(c16^(row&7))*8 ..+7]
// V image (transposed):     byte(d*128  + c8*16)  holds V[(c8^(d&7))*8 + t][d], t=0..7
// LINEAR global->LDS copy then yields the XOR-swizzled layout (rule #21).
__global__ __launch_bounds__(512) void prep(const float* __restrict__ k,
                                            const float* __restrict__ v,
                                            bf16* __restrict__ kws,
                                            bf16* __restrict__ vws) {
  __shared__ float Vf[KT * 129];  // stride 129: conflict-free column reads
  const int blk = blockIdx.x;     // 512 = 16 (b*hkv) * 32 tiles
  const int bhkv = blk >> 5, tile = blk & 31;
  const float* ks = k + ((size_t)bhkv * S_ + (size_t)tile * KT) * D_;
  const float* vs = v + ((size_t)bhkv * S_ + (size_t)tile * KT) * D_;
  bf16* kd = kws + (size_t)blk * TILE_ELEMS;
  bf16* vd = vws + (size_t)blk * TILE_ELEMS;
  const int t = threadIdx.x;
#pragma unroll
  for (int i = 0; i < 4; ++i) {  // coalesced V tile -> LDS
    int c = t + 512 * i, row = c >> 5, c4 = c & 31;
    *(float4*)&Vf[row * 129 + c4 * 4] = *(const float4*)(vs + row * D_ + c4 * 4);
  }
#pragma unroll
  for (int i = 0; i < 2; ++i) {  // K image (coalesced read, linear write)
    int chunk = t + 512 * i, row = chunk >> 4, c16 = chunk & 15;
    int e = (c16 ^ (row & 7)) << 3;
    *(bf16x8*)&kd[chunk * 8] = cvt8(ks + row * D_ + e);
  }
  __syncthreads();
#pragma unroll
  for (int i = 0; i < 2; ++i) {  // V image from LDS transpose
    int chunk = t + 512 * i, d = chunk >> 3, c8 = chunk & 7;
    int k0 = (c8 ^ (d & 7)) << 3;
    bf16x8 val;
#pragma unroll
    for (int kk = 0; kk < 8; ++kk) val[kk] = (bf16)Vf[(k0 + kk) * 129 + d];
    *(bf16x8*)&vd[chunk * 8] = val;
  }
}

// ---------------- main: flash attention, QT=128 / 8 waves / 512 threads -----
// R9 = R7 structure exactly (K double-buffered, V single-buffered, counted
// vmcnt, launch_bounds (512,4): VGPR=60, zero spill) + LPT block order:
// tqt = 15-(bid>>6) dispatches all 64 longest (32-iter) blocks first, short
// blocks backfill the tail. R8's (512,6) capped regs at ~85/wave and spilled
// ~1.5 GB/dispatch to scratch (WRITE_SIZE 65->987 MB) -- 3 blocks/CU is
// unreachable for this register footprint; occupancy gains must come from
// makespan packing instead.
__global__ __launch_bounds__(512, 4) void fa_mfma(
    const float* __restrict__ q, const bf16* __restrict__ kws,
    const bf16* __restrict__ vws, float* __restrict__ out) {
  __shared__ bf16 Kb2[2][TILE_ELEMS];  // 32 KiB
  __shared__ bf16 Vb[TILE_ELEMS];      // 16 KiB
  __shared__ bf16 Ps[8 * 16 * PST];    // 18 KiB

  const int tid = threadIdx.x, wave = tid >> 6, lane = tid & 63;
  const int col = lane & 15, quad = lane >> 4;
  const int bid = blockIdx.x;
  const int tqt = (NQT - 1) - (bid >> 6);  // LPT: longest blocks first
  const int bh = bid & 63, b = bh >> 5, h = bh & 31, hkv = h >> 2;  // GQA h/4
  const int bhkv = b * HKV_ + hkv;

  const float* qh = q + (size_t)(b * H_ + h) * S_ * D_;
  float* oh = out + (size_t)(b * H_ + h) * S_ * D_;
  const bf16* kg = kws + (size_t)(bhkv * NTILES) * TILE_ELEMS;
  const bf16* vg = vws + (size_t)(bhkv * NTILES) * TILE_ELEMS;
  const int q0 = tqt * QT;
  const int jmax = 2 * tqt + 1;  // k-tiles 0..jmax cover keys < q0+QT

  // Q A-fragments: A[m=col][k=quad*8+j], chunk ks covers d in [ks*32,ks*32+32)
  bf16x8 qf[4];
  {
    const float* qrow = qh + (size_t)(q0 + wave * 16 + col) * D_ + quad * 8;
#pragma unroll
    for (int ks = 0; ks < 4; ++ks) qf[ks] = cvt8(qrow + ks * 32);
  }

  f32x4 o[8];
#pragma unroll
  for (int i = 0; i < 8; ++i) o[i] = (f32x4){0.f, 0.f, 0.f, 0.f};
  float m_i[4], lp[4];  // lp: per-lane PARTIAL l; reduced in the epilogue
#pragma unroll
  for (int r = 0; r < 4; ++r) { m_i[r] = NEG_BIG; lp[r] = 0.f; }

  // swizzled-read offsets (same involution as prep): qx[ks] for b128 reads
  const int qoff = (quad * 16) ^ ((col & 7) << 4);
  const int qx[4] = {qoff, qoff ^ 64, qoff ^ 128, qoff ^ 192};

  const int stoff = tid * 16;  // 512 threads x 16B = 8 KiB per pass

  auto stageK = [&](int j, int buf) {
    const char* src = (const char*)(kg + (size_t)j * TILE_ELEMS) + stoff;
    char* dst = (char*)Kb2[buf] + stoff;
#pragma unroll
    for (int i = 0; i < 2; ++i)
      __builtin_amdgcn_global_load_lds((glb_u32*)(src + i * 8192),
                                       (lds_u32*)(dst + i * 8192), 16, 0, 0);
  };
  auto stageV = [&](int j) {
    const char* src = (const char*)(vg + (size_t)j * TILE_ELEMS) + stoff;
    char* dst = (char*)Vb + stoff;
#pragma unroll
    for (int i = 0; i < 2; ++i)
      __builtin_amdgcn_global_load_lds((glb_u32*)(src + i * 8192),
                                       (lds_u32*)(dst + i * 8192), 16, 0, 0);
  };

  stageK(0, 0);
  asm volatile("s_waitcnt vmcnt(0)" ::: "memory");
  __builtin_amdgcn_s_barrier();
  __builtin_amdgcn_sched_barrier(0);

  for (int j = 0; j <= jmax; ++j) {
    const int cur = j & 1;
    stageV(j);                             // needed at mid barrier
    if (j < jmax) stageK(j + 1, cur ^ 1);  // needed at end barrier

    const char* Kb = (const char*)Kb2[cur];

    // ---- S strip: 16 q-rows x 64 keys per wave (swizzled b128 reads) ----
    float s[4][4];  // S[qrow=wave*16+quad*4+r][key=nt*16+col]
    __builtin_amdgcn_s_setprio(1);
#pragma unroll
    for (int nt = 0; nt < 4; ++nt) {
      const char* An = Kb + (nt * 16 + col) * 256;
      f32x4 acc = (f32x4){0.f, 0.f, 0.f, 0.f};
#pragma unroll
      for (int ks = 0; ks < 4; ++ks) {
        bf16x8 kf = *(const bf16x8*)(An + qx[ks]);
        acc = __builtin_amdgcn_mfma_f32_16x16x32_bf16(qf[ks], kf, acc, 0, 0, 0);
      }
#pragma unroll
      for (int r = 0; r < 4; ++r) s[nt][r] = acc[r] * SCL;
    }
    __builtin_amdgcn_s_setprio(0);

    // causal mask: only the last two k-tiles intersect the diagonal
    if (j >= 2 * tqt) {
      const int rel = j * KT - q0 - wave * 16;  // key offset vs wave's row base
#pragma unroll
      for (int nt = 0; nt < 4; ++nt) {
        int kc = rel + nt * 16 + col;
#pragma unroll
        for (int r = 0; r < 4; ++r)
          if (kc > quad * 4 + r) s[nt][r] = NEG_BIG;
      }
    }

    // ---- online softmax: max-reduce only; l kept as per-lane partial ----
    float mx[4];
#pragma unroll
    for (int r = 0; r < 4; ++r) {
      float m0 = fmaxf(fmaxf(s[0][r], s[1][r]), fmaxf(s[2][r], s[3][r]));
#pragma unroll
      for (int off = 1; off < 16; off <<= 1)
        m0 = fmaxf(m0, __shfl_xor(m0, off, 64));
      mx[r] = m0;  // uniform across the row's 16 lanes
    }
    // T13 defer-max: wave-uniform skip of the O-rescale while growth < THR
    float need = fmaxf(fmaxf(mx[0] - m_i[0], mx[1] - m_i[1]),
                       fmaxf(mx[2] - m_i[2], mx[3] - m_i[3]));
    if (__any(need > DEFER_THR)) {
#pragma unroll
      for (int r = 0; r < 4; ++r) {
        float mnew = fmaxf(m_i[r], mx[r]);
        float alpha = exp2f(m_i[r] - mnew);
        lp[r] *= alpha;
        m_i[r] = mnew;
#pragma unroll
        for (int dt = 0; dt < 8; ++dt) o[dt][r] *= alpha;
      }
    }

    float p[4][4];
#pragma unroll
    for (int r = 0; r < 4; ++r) {
      float rs = 0.f;
#pragma unroll
      for (int nt = 0; nt < 4; ++nt) {
        float pv = exp2f(s[nt][r] - m_i[r]);  // bounded by 2^THR
        p[nt][r] = pv;
        rs += pv;
      }
      lp[r] += rs;
    }

    // ---- P: C-layout -> A-layout via per-wave LDS round trip ----
    bf16* pw = &Ps[wave * 16 * PST];
#pragma unroll
    for (int nt = 0; nt < 4; ++nt)
#pragma unroll
      for (int r = 0; r < 4; ++r)
        pw[(quad * 4 + r) * PST + nt * 16 + col] = (bf16)p[nt][r];

    // mid barrier (counted): V(j) + own P visible; K(j+1) stays in flight
    if (j < jmax)
      asm volatile("s_waitcnt vmcnt(2) lgkmcnt(0)" ::: "memory");
    else
      asm volatile("s_waitcnt vmcnt(0) lgkmcnt(0)" ::: "memory");
    __builtin_amdgcn_s_barrier();
    __builtin_amdgcn_sched_barrier(0);

    bf16x8 pf[2];
#pragma unroll
    for (int ks = 0; ks < 2; ++ks)
      pf[ks] = *(const bf16x8*)&pw[col * PST + ks * 32 + quad * 8];

    // ---- O += P·V (swizzled single b128 reads) ----
    __builtin_amdgcn_s_setprio(1);
#pragma unroll
    for (int dt = 0; dt < 8; ++dt) {
      const char* Av = (const char*)Vb + (dt * 16 + col) * 128;
#pragma unroll
      for (int ks = 0; ks < 2; ++ks) {
        bf16x8 vf = *(const bf16x8*)(Av + qx[ks]);
        o[dt] = __builtin_amdgcn_mfma_f32_16x16x32_bf16(pf[ks], vf, o[dt], 0, 0, 0);
      }
    }
    __builtin_amdgcn_s_setprio(0);

    // end barrier: K(j+1) drained (covered by PV); LDS safe to overwrite
    if (j < jmax) {
      asm volatile("s_waitcnt vmcnt(0)" ::: "memory");
      __builtin_amdgcn_s_barrier();
      __builtin_amdgcn_sched_barrier(0);
    }
  }

  // ---- epilogue: reduce partial l across the row's 16 lanes, O / l ----
#pragma unroll
  for (int r = 0; r < 4; ++r) {
    float l = lp[r];
#pragma unroll
    for (int off = 1; off < 16; off <<= 1)
      l += __shfl_xor(l, off, 64);
    float inv = 1.f / l;
    float* orow = oh + (size_t)(q0 + wave * 16 + quad * 4 + r) * D_;
#pragma unroll
    for (int dt = 0; dt < 8; ++dt)
      orow[dt * 16 + col] = o[dt][r] * inv;
  }
}

extern "C" void kernel_launch(void* const* d_in, const int* in_sizes, int n_in,
                              void* d_out, int out_size, void* d_ws, size_t ws_size,
                              hipStream_t stream) {
  const int QN = B_ * H_ * S_ * D_;
  int qi, ki, vi;
  if (in_sizes[0] == QN)      { qi = 0; ki = 1; vi = 2; }
  else if (in_sizes[1] == QN) { qi = 1; ki = 0; vi = 2; }
  else                        { qi = 2; ki = 0; vi = 1; }
  const float* q = (const float*)d_in[qi];
  const float* k = (const float*)d_in[ki];
  const float* v = (const float*)d_in[vi];
  float* out = (float*)d_out;

  // ws: K images then V images; 2 * 16*32*8192 bf16 = 16 MiB total
  bf16* kws = (bf16*)d_ws;
  bf16* vws = kws + (size_t)(B_ * HKV_) * NTILES * TILE_ELEMS;

  prep<<<dim3(B_ * HKV_ * NTILES), dim3(512), 0, stream>>>(k, v, kws, vws);
  fa_mfma<<<dim3(B_ * H_ * NQT), dim3(512), 0, stream>>>(q, kws, vws, out);
}

// Round 10
// 241.137 us; speedup vs baseline: 2.0113x; 1.0614x over previous
//
#include <hip/hip_runtime.h>
#include <hip/hip_bf16.h>
#include <cstdint>

typedef __bf16 bf16;
typedef __bf16 bf16x8 __attribute__((ext_vector_type(8)));
typedef float f32x4 __attribute__((ext_vector_type(4)));
typedef unsigned int u32;
typedef __attribute__((address_space(3))) uint32_t lds_u32;
typedef const __attribute__((address_space(1))) uint32_t glb_u32;

#define B_ 2
#define H_ 32
#define HKV_ 8
#define S_ 2048
#define D_ 128
#define QT 128                 // 128 q-rows/block, 8 waves
#define KT 64
#define NQT (S_ / QT)          // 16 q-tiles
#define NTILES (S_ / KT)       // 32 k-tiles
#define TILE_ELEMS (KT * D_)   // 8192 bf16 = 16 KiB per tile image
#define NEG_BIG (-1.0e30f)
#define SCL 0.12751745f        // (1/sqrt(128)) * log2(e): softmax in exp2 domain
#define DEFER_THR 8.0f         // T13: skip O-rescale while max grows < 2^8

__device__ __forceinline__ bf16x8 cvt8p(float4 a, float4 b) {
  bf16x8 r = {(bf16)a.x, (bf16)a.y, (bf16)a.z, (bf16)a.w,
              (bf16)b.x, (bf16)b.y, (bf16)b.z, (bf16)b.w};
  return r;
}
__device__ __forceinline__ bf16x8 cvt8(const float* f) {
  return cvt8p(*(const float4*)f, *(const float4*)(f + 4));
}
__device__ __forceinline__ u32 pk2(float lo, float hi) {  // plain casts (m240)
  union { bf16 h[2]; u32 w; } u;
  u.h[0] = (bf16)lo; u.h[1] = (bf16)hi;
  return u.w;
}

// ---------------- pre-pass: build swizzled bf16 LDS tile images in ws -------
// K image, per (bhkv,tile): byte(row*256 + c16*16) holds K[row][(c16^(row&7))*8 ..+7]
// V image (transposed):     byte(d*128  + c8*16)  holds V[(c8^(d&7))*8 + t][d], t=0..7
__global__ __launch_bounds__(512) void prep(const float* __restrict__ k,
                                            const float* __restrict__ v,
                                            bf16* __restrict__ kws,
                                            bf16* __restrict__ vws) {
  __shared__ float Vf[KT * 129];  // stride 129: conflict-free column reads
  const int blk = blockIdx.x;     // 512 = 16 (b*hkv) * 32 tiles
  const int bhkv = blk >> 5, tile = blk & 31;
  const float* ks = k + ((size_t)bhkv * S_ + (size_t)tile * KT) * D_;
  const float* vs = v + ((size_t)bhkv * S_ + (size_t)tile * KT) * D_;
  bf16* kd = kws + (size_t)blk * TILE_ELEMS;
  bf16* vd = vws + (size_t)blk * TILE_ELEMS;
  const int t = threadIdx.x;
#pragma unroll
  for (int i = 0; i < 4; ++i) {  // coalesced V tile -> LDS
    int c = t + 512 * i, row = c >> 5, c4 = c & 31;
    *(float4*)&Vf[row * 129 + c4 * 4] = *(const float4*)(vs + row * D_ + c4 * 4);
  }
#pragma unroll
  for (int i = 0; i < 2; ++i) {  // K image (coalesced read, linear write)
    int chunk = t + 512 * i, row = chunk >> 4, c16 = chunk & 15;
    int e = (c16 ^ (row & 7)) << 3;
    *(bf16x8*)&kd[chunk * 8] = cvt8(ks + row * D_ + e);
  }
  __syncthreads();
#pragma unroll
  for (int i = 0; i < 2; ++i) {  // V image from LDS transpose
    int chunk = t + 512 * i, d = chunk >> 3, c8 = chunk & 7;
    int k0 = (c8 ^ (d & 7)) << 3;
    bf16x8 val;
#pragma unroll
    for (int kk = 0; kk < 8; ++kk) val[kk] = (bf16)Vf[(k0 + kk) * 129 + d];
    *(bf16x8*)&vd[chunk * 8] = val;
  }
}

// ---------------- main: flash attention, QT=128 / 8 waves / 512 threads -----
// R10 = R9 + T12 swapped-operand MFMA softmax:
//   QK: mfma(kf,qf) -> lane holds S[key=nt*16+quad*4+r][qrow=col] -- softmax is
//   lane-local (15 fmax + 2 shfl; scalar m,l). P redistributed to the PV
//   B-operand IN REGISTERS (pk2 packs + permlane32_swap + shfl_xor16 + cndmask)
//   -- the P LDS round trip (16 ds_write_b16 + lgkm + 2 ds_read) is deleted.
//   PV: mfma(vf,pf) -> O[qrow=col][d] aligned with softmax state; epilogue is
//   8 float4 stores. Ps LDS gone -> 48 KiB total.
__global__ __launch_bounds__(512, 4) void fa_mfma(
    const float* __restrict__ q, const bf16* __restrict__ kws,
    const bf16* __restrict__ vws, float* __restrict__ out) {
  __shared__ bf16 Kb2[2][TILE_ELEMS];  // 32 KiB
  __shared__ bf16 Vb[TILE_ELEMS];      // 16 KiB

  const int tid = threadIdx.x, wave = tid >> 6, lane = tid & 63;
  const int col = lane & 15, quad = lane >> 4;
  const int bid = blockIdx.x;
  const int tqt = (NQT - 1) - (bid >> 6);  // LPT: longest blocks first
  const int bh = bid & 63, b = bh >> 5, h = bh & 31, hkv = h >> 2;  // GQA h/4
  const int bhkv = b * HKV_ + hkv;

  const float* qh = q + (size_t)(b * H_ + h) * S_ * D_;
  float* oh = out + (size_t)(b * H_ + h) * S_ * D_;
  const bf16* kg = kws + (size_t)(bhkv * NTILES) * TILE_ELEMS;
  const bf16* vg = vws + (size_t)(bhkv * NTILES) * TILE_ELEMS;
  const int q0 = tqt * QT;
  const int jmax = 2 * tqt + 1;  // k-tiles 0..jmax cover keys < q0+QT

  // Q fragments (used as the MFMA B-operand now; same data/lane map as before)
  bf16x8 qf[4];
  {
    const float* qrow = qh + (size_t)(q0 + wave * 16 + col) * D_ + quad * 8;
#pragma unroll
    for (int ks = 0; ks < 4; ++ks) qf[ks] = cvt8(qrow + ks * 32);
  }

  f32x4 o[8];  // O[qrow=col][d = dt*16 + quad*4 + r]
#pragma unroll
  for (int i = 0; i < 8; ++i) o[i] = (f32x4){0.f, 0.f, 0.f, 0.f};
  float m_i = NEG_BIG, lp = 0.f;  // scalar per lane (q-row = col)

  // swizzled-read offsets (same involution as prep)
  const int qoff = (quad * 16) ^ ((col & 7) << 4);
  const int qx[4] = {qoff, qoff ^ 64, qoff ^ 128, qoff ^ 192};

  const int stoff = tid * 16;  // 512 threads x 16B = 8 KiB per pass

  auto stageK = [&](int j, int buf) {
    const char* src = (const char*)(kg + (size_t)j * TILE_ELEMS) + stoff;
    char* dst = (char*)Kb2[buf] + stoff;
#pragma unroll
    for (int i = 0; i < 2; ++i)
      __builtin_amdgcn_global_load_lds((glb_u32*)(src + i * 8192),
                                       (lds_u32*)(dst + i * 8192), 16, 0, 0);
  };
  auto stageV = [&](int j) {
    const char* src = (const char*)(vg + (size_t)j * TILE_ELEMS) + stoff;
    char* dst = (char*)Vb + stoff;
#pragma unroll
    for (int i = 0; i < 2; ++i)
      __builtin_amdgcn_global_load_lds((glb_u32*)(src + i * 8192),
                                       (lds_u32*)(dst + i * 8192), 16, 0, 0);
  };

  stageK(0, 0);
  asm volatile("s_waitcnt vmcnt(0)" ::: "memory");
  __builtin_amdgcn_s_barrier();
  __builtin_amdgcn_sched_barrier(0);

  for (int j = 0; j <= jmax; ++j) {
    const int cur = j & 1;
    stageV(j);                             // needed at mid barrier
    if (j < jmax) stageK(j + 1, cur ^ 1);  // needed at end barrier

    const char* Kb = (const char*)Kb2[cur];

    // ---- S strip, SWAPPED: s[nt][r] = S[key=nt*16+quad*4+r][qrow=col] ----
    float s[4][4];
    __builtin_amdgcn_s_setprio(1);
#pragma unroll
    for (int nt = 0; nt < 4; ++nt) {
      const char* An = Kb + (nt * 16 + col) * 256;
      f32x4 acc = (f32x4){0.f, 0.f, 0.f, 0.f};
#pragma unroll
      for (int ks = 0; ks < 4; ++ks) {
        bf16x8 kf = *(const bf16x8*)(An + qx[ks]);
        acc = __builtin_amdgcn_mfma_f32_16x16x32_bf16(kf, qf[ks], acc, 0, 0, 0);
      }
#pragma unroll
      for (int r = 0; r < 4; ++r) s[nt][r] = acc[r] * SCL;
    }
    __builtin_amdgcn_s_setprio(0);

    // causal mask: key kc = rel + nt*16 + quad*4 + r vs qrow = col
    if (j >= 2 * tqt) {
      const int rel = j * KT - q0 - wave * 16;
#pragma unroll
      for (int nt = 0; nt < 4; ++nt)
#pragma unroll
        for (int r = 0; r < 4; ++r)
          if (rel + nt * 16 + quad * 4 + r > col) s[nt][r] = NEG_BIG;
    }

    // ---- softmax: lane-local max over 16 + 2 quad-reduce shuffles ----
    float mx = s[0][0];
#pragma unroll
    for (int nt = 0; nt < 4; ++nt)
#pragma unroll
      for (int r = 0; r < 4; ++r) mx = fmaxf(mx, s[nt][r]);
    mx = fmaxf(mx, __shfl_xor(mx, 16, 64));
    mx = fmaxf(mx, __shfl_xor(mx, 32, 64));  // uniform across quads @ col

    if (__any(mx - m_i > DEFER_THR)) {  // T13 defer-max
      float mnew = fmaxf(m_i, mx);
      float alpha = exp2f(m_i - mnew);
      lp *= alpha;
      m_i = mnew;
#pragma unroll
      for (int dt = 0; dt < 8; ++dt) o[dt] *= alpha;
    }

    float rs = 0.f;
#pragma unroll
    for (int nt = 0; nt < 4; ++nt)
#pragma unroll
      for (int r = 0; r < 4; ++r) {
        s[nt][r] = exp2f(s[nt][r] - m_i);  // bounded by 2^THR
        rs += s[nt][r];
      }
    lp += rs;

    // ---- P -> PV B-operand, in-register (T12) ----
    // pk_[n][p] = pack(P[key=16n+4q+2p], P[key=16n+4q+2p+1]) at quad q.
    // pf[ks] word w needs pk_[2ks+(t>>1)][w&1] from quad q_s=2(t&1)+(w>>1):
    //   permlane32_swap(Q,R): Q'=[Q0,Q1,R0,R1], R'=[Q2,Q3,R2,R3] (per quad)
    //   w{0,1}: t even -> Q'(self); t odd -> shfl_xor16(R') (=Q@q2 / R@q2)
    //   w{2,3}: t even -> shfl_xor16(Q'); t odd -> R'(self)
    u32 pk_[4][2];
#pragma unroll
    for (int nt = 0; nt < 4; ++nt) {
      pk_[nt][0] = pk2(s[nt][0], s[nt][1]);
      pk_[nt][1] = pk2(s[nt][2], s[nt][3]);
    }
    const bool oddq = (quad & 1);
    union W8 { u32 w[4]; bf16x8 h; } pf[2];
#pragma unroll
    for (int ks = 0; ks < 2; ++ks)
#pragma unroll
      for (int p = 0; p < 2; ++p) {
        auto sw = __builtin_amdgcn_permlane32_swap(pk_[2 * ks][p],
                                                   pk_[2 * ks + 1][p],
                                                   false, false);
        u32 Qp = (u32)sw[0], Rp = (u32)sw[1];
        u32 Tp = (u32)__shfl_xor((int)Qp, 16, 64);
        u32 Sp = (u32)__shfl_xor((int)Rp, 16, 64);
        pf[ks].w[p] = oddq ? Sp : Qp;      // words 0,1
        pf[ks].w[2 + p] = oddq ? Rp : Tp;  // words 2,3
      }

    // mid barrier (counted): V(j) visible; K(j+1)'s 2 loads stay in flight
    if (j < jmax)
      asm volatile("s_waitcnt vmcnt(2)" ::: "memory");
    else
      asm volatile("s_waitcnt vmcnt(0)" ::: "memory");
    __builtin_amdgcn_s_barrier();
    __builtin_amdgcn_sched_barrier(0);

    // ---- O += V^T·P (swapped): o[dt] rows = d, cols = qrow ----
    __builtin_amdgcn_s_setprio(1);
#pragma unroll
    for (int dt = 0; dt < 8; ++dt) {
      const char* Av = (const char*)Vb + (dt * 16 + col) * 128;
#pragma unroll
      for (int ks = 0; ks < 2; ++ks) {
        bf16x8 vf = *(const bf16x8*)(Av + qx[ks]);
        o[dt] = __builtin_amdgcn_mfma_f32_16x16x32_bf16(vf, pf[ks].h, o[dt], 0, 0, 0);
      }
    }
    __builtin_amdgcn_s_setprio(0);

    // end barrier: K(j+1) drained (covered by PV); Vb safe to overwrite
    if (j < jmax) {
      asm volatile("s_waitcnt vmcnt(0)" ::: "memory");
      __builtin_amdgcn_s_barrier();
      __builtin_amdgcn_sched_barrier(0);
    }
  }

  // ---- epilogue: l quad-reduce (2 shfl), O/l, float4 stores ----
  float l = lp;
  l += __shfl_xor(l, 16, 64);
  l += __shfl_xor(l, 32, 64);
  const float inv = 1.f / l;
  float* orow = oh + (size_t)(q0 + wave * 16 + col) * D_;
#pragma unroll
  for (int dt = 0; dt < 8; ++dt) {
    f32x4 vout = o[dt] * inv;
    *(f32x4*)&orow[dt * 16 + quad * 4] = vout;
  }
}

extern "C" void kernel_launch(void* const* d_in, const int* in_sizes, int n_in,
                              void* d_out, int out_size, void* d_ws, size_t ws_size,
                              hipStream_t stream) {
  const int QN = B_ * H_ * S_ * D_;
  int qi, ki, vi;
  if (in_sizes[0] == QN)      { qi = 0; ki = 1; vi = 2; }
  else if (in_sizes[1] == QN) { qi = 1; ki = 0; vi = 2; }
  else                        { qi = 2; ki = 0; vi = 1; }
  const float* q = (const float*)d_in[qi];
  const float* k = (const float*)d_in[ki];
  const float* v = (const float*)d_in[vi];
  float* out = (float*)d_out;

  // ws: K images then V images; 2 * 16*32*8192 bf16 = 16 MiB total
  bf16* kws = (bf16*)d_ws;
  bf16* vws = kws + (size_t)(B_ * HKV_) * NTILES * TILE_ELEMS;

  prep<<<dim3(B_ * HKV_ * NTILES), dim3(512), 0, stream>>>(k, v, kws, vws);
  fa_mfma<<<dim3(B_ * H_ * NQT), dim3(512), 0, stream>>>(q, kws, vws, out);
}